// Round 5
// baseline (449.222 us; speedup 1.0000x reference)
//
#include <hip/hip_runtime.h>
#include <hip/hip_bf16.h>

// N=1e6 nodes, V=6e5 var nodes, H=128.
constexpr int H = 128;
constexpr int V = 600000;
constexpr int NTOT = 1000000;

typedef short bf16x8 __attribute__((ext_vector_type(8)));   // 8 bf16 = 4 VGPR
typedef float f32x4 __attribute__((ext_vector_type(4)));

__device__ inline short f2bf(float f) {  // round-to-nearest-even bf16
    unsigned u = __float_as_uint(f);
    u += 0x7FFF + ((u >> 16) & 1);
    return (short)(u >> 16);
}

// uc[h]=u, uc[128+h]=c :  logits[i][h] = vf_i . W1[:,h] + llr_i*u[h] + c[h]
// uc[256..383]=W_llr, uc[384..511]=b_llr (staged for the main kernel)
__global__ void precompute_uc_kernel(const float* __restrict__ W_llr,
                                     const float* __restrict__ b_llr,
                                     const float* __restrict__ W_gate,
                                     const float* __restrict__ b_gate,
                                     float* __restrict__ uc) {
    int h = threadIdx.x;  // 128 threads
    float u = 0.0f, c = 0.0f;
    for (int k = 0; k < H; ++k) {
        float w2 = W_gate[(size_t)(H + k) * H + h];
        u += W_llr[k] * w2;
        c += b_llr[k] * w2;
    }
    uc[h] = u;
    uc[H + h] = c + b_gate[h];
    uc[2 * H + h] = W_llr[h];
    uc[3 * H + h] = b_llr[h];
}

// LDS byte layout:
//   [0, 34816)     Wt: 128 n-rows x 272 B (bf16 k-major); after B-frag preload
//                  this region is reused as the A-tile (64 rows x 272 B).
//   [34816, 36864) vec: u[128], c[128], W_llr[128], b_llr[128] (fp32)
//   [36864, 37120) llr tile (64 fp32)
#define LDS_BYTES 37120
#define VEC_OFF 34816
#define LLR_OFF 36864
#define ROWB 272  // 16-aligned; 272/4 mod 32 = 4 -> 2-way bank aliasing (free)

__global__ __launch_bounds__(256, 3) void fused_residual_llr_kernel(
    const float* __restrict__ nf,      // [N][H]
    const float* __restrict__ llr,     // [V]
    const float* __restrict__ W_gate,  // [2H][H]
    const float* __restrict__ uc,      // [4H]
    float* __restrict__ out) {         // [N][H]
    int b = blockIdx.x;
    int tid = threadIdx.x;

    if ((b & 3) == 3) {
        // ---- copy role: rows V..N. 4 independent float4 pairs in flight.
        // n4 = 12.8M, 625 copy blocks * 256 thr: stride=160000, 80 sweeps = 20x4 exact.
        size_t base = (size_t)V * H;
        const float4* src = reinterpret_cast<const float4*>(nf + base);
        float4* dst = reinterpret_cast<float4*>(out + base);
        size_t i0 = (size_t)(b >> 2) * 256 + tid;
        const size_t stride = 625u * 256u;  // 160000
#pragma unroll 1
        for (int s = 0; s < 20; ++s) {
            size_t i = i0 + (size_t)s * (stride * 4);
            float4 v0 = src[i];
            float4 v1 = src[i + stride];
            float4 v2 = src[i + 2 * stride];
            float4 v3 = src[i + 3 * stride];
            dst[i] = v0;
            dst[i + stride] = v1;
            dst[i + 2 * stride] = v2;
            dst[i + 3 * stride] = v3;
        }
        return;
    }
    int cb = (b >> 2) * 3 + (b & 3);  // compute-block index 0..1874

    __shared__ __align__(16) char lds[LDS_BYTES];
    float* vecf = reinterpret_cast<float*>(lds + VEC_OFF);
    float* llrl = reinterpret_cast<float*>(lds + LLR_OFF);

    int lane = tid & 63;
    int w = tid >> 6;          // wave 0..3
    int wr = w >> 1;           // row half (32 rows)
    int wc = w & 1;            // col half (64 cols)
    int l15 = lane & 15;
    int l4 = lane >> 4;

    // ---- T14 prologue: issue tile-0 loads FIRST (latency hides under W stage)
    int row0 = cb * 5 * 64;
    float4 st[8];
#pragma unroll
    for (int j = 0; j < 8; ++j) {
        int idx = tid + 256 * j;
        int r = idx >> 5, c4 = idx & 31;
        st[j] = reinterpret_cast<const float4*>(nf)[(size_t)(row0 + r) * 32 + c4];
    }
    float llr0 = (tid < 64) ? llr[row0 + tid] : 0.0f;

    // ---- stage W1^T (bf16) + vectors ----
#pragma unroll 4
    for (int j = 0; j < 16; ++j) {  // 4096 float4 of W1
        int idx = tid + 256 * j;
        int k = idx >> 5, c4 = idx & 31;
        float4 wv = reinterpret_cast<const float4*>(W_gate)[(size_t)k * 32 + c4];
        float wa[4] = {wv.x, wv.y, wv.z, wv.w};
#pragma unroll
        for (int e = 0; e < 4; ++e) {
            int n = c4 * 4 + e;
            *reinterpret_cast<short*>(lds + n * ROWB + k * 2) = f2bf(wa[e]);
        }
    }
    if (tid < 128) {
        vecf[tid]       = uc[tid];
        vecf[128 + tid] = uc[128 + tid];
        vecf[256 + tid] = uc[256 + tid];
        vecf[384 + tid] = uc[384 + tid];
    }
    __syncthreads();

    // ---- preload B fragments (held in VGPRs across all tiles) ----
    bf16x8 Bf[4][4];  // [kk][nfr]
#pragma unroll
    for (int kk = 0; kk < 4; ++kk)
#pragma unroll
        for (int nfr = 0; nfr < 4; ++nfr) {
            int n = wc * 64 + nfr * 16 + l15;
            Bf[kk][nfr] = *reinterpret_cast<const bf16x8*>(
                lds + n * ROWB + kk * 64 + l4 * 16);
        }
    __syncthreads();  // B reads complete before A-tile overwrites W region

    // ---- write tile 0 to LDS ----
#pragma unroll
    for (int j = 0; j < 8; ++j) {
        int idx = tid + 256 * j;
        int r = idx >> 5, c4 = idx & 31;
        short4 p;
        p.x = f2bf(st[j].x); p.y = f2bf(st[j].y);
        p.z = f2bf(st[j].z); p.w = f2bf(st[j].w);
        *reinterpret_cast<short4*>(lds + r * ROWB + c4 * 8) = p;
    }
    if (tid < 64) llrl[tid] = llr0;
    __syncthreads();

    const float* u_l = vecf;
    const float* c_l = vecf + 128;

    // ---- tile loop: LDS holds tile t at loop top; prefetch t+1 in regs ----
#pragma unroll 1
    for (int t = 0; t < 5; ++t) {
        int rowBase = (cb * 5 + t) * 64;

        // (a) issue prefetch for tile t+1 (flies under MFMA + epilogue)
        float llrn = 0.0f;
        if (t < 4) {
            int rowN = rowBase + 64;
#pragma unroll
            for (int j = 0; j < 8; ++j) {
                int idx = tid + 256 * j;
                int r = idx >> 5, c4 = idx & 31;
                st[j] = reinterpret_cast<const float4*>(nf)[(size_t)(rowN + r) * 32 + c4];
            }
            if (tid < 64) llrn = llr[rowN + tid];
        }

        // (b) MFMA: wave computes 32 rows x 64 cols of tile t
        f32x4 acc[2][4];
#pragma unroll
        for (int mf = 0; mf < 2; ++mf)
#pragma unroll
            for (int nfr = 0; nfr < 4; ++nfr)
                acc[mf][nfr] = (f32x4){0.f, 0.f, 0.f, 0.f};

#pragma unroll
        for (int kk = 0; kk < 4; ++kk) {
            bf16x8 a0 = *reinterpret_cast<const bf16x8*>(
                lds + (wr * 32 + 0 + l15) * ROWB + kk * 64 + l4 * 16);
            bf16x8 a1 = *reinterpret_cast<const bf16x8*>(
                lds + (wr * 32 + 16 + l15) * ROWB + kk * 64 + l4 * 16);
#pragma unroll
            for (int nfr = 0; nfr < 4; ++nfr) {
                acc[0][nfr] = __builtin_amdgcn_mfma_f32_16x16x32_bf16(
                    a0, Bf[kk][nfr], acc[0][nfr], 0, 0, 0);
                acc[1][nfr] = __builtin_amdgcn_mfma_f32_16x16x32_bf16(
                    a1, Bf[kk][nfr], acc[1][nfr], 0, 0, 0);
            }
        }

        // (c) epilogue: + llr*u + c, sigmoid, blend with vf (bf16 LDS), store
#pragma unroll
        for (int mf = 0; mf < 2; ++mf) {
#pragma unroll
            for (int reg = 0; reg < 4; ++reg) {
                int rloc = wr * 32 + mf * 16 + l4 * 4 + reg;
                float l_r = llrl[rloc];
#pragma unroll
                for (int nfr = 0; nfr < 4; ++nfr) {
                    int col = wc * 64 + nfr * 16 + l15;
                    float x = acc[mf][nfr][reg] + fmaf(l_r, u_l[col], c_l[col]);
                    float g = 1.0f / (1.0f + __expf(-x));
                    unsigned short vs = *reinterpret_cast<const unsigned short*>(
                        lds + rloc * ROWB + col * 2);
                    float vf = __uint_as_float((unsigned)vs << 16);
                    float lf = fmaf(l_r, vecf[256 + col], vecf[384 + col]);
                    float o = fmaf(g, lf - vf, vf);
                    out[(size_t)(rowBase + rloc) * H + col] = o;
                }
            }
        }

        // (d) publish tile t+1 to LDS
        if (t < 4) {
            __syncthreads();  // everyone done reading tile t (drains st loads too)
#pragma unroll
            for (int j = 0; j < 8; ++j) {
                int idx = tid + 256 * j;
                int r = idx >> 5, c4 = idx & 31;
                short4 p;
                p.x = f2bf(st[j].x); p.y = f2bf(st[j].y);
                p.z = f2bf(st[j].z); p.w = f2bf(st[j].w);
                *reinterpret_cast<short4*>(lds + r * ROWB + c4 * 8) = p;
            }
            if (tid < 64) llrl[tid] = llrn;
            __syncthreads();
        }
    }
}

extern "C" void kernel_launch(void* const* d_in, const int* in_sizes, int n_in,
                              void* d_out, int out_size, void* d_ws, size_t ws_size,
                              hipStream_t stream) {
    const float* nf     = (const float*)d_in[0];
    const float* llr    = (const float*)d_in[1];
    const float* W_llr  = (const float*)d_in[2];
    const float* b_llr  = (const float*)d_in[3];
    const float* W_gate = (const float*)d_in[4];
    const float* b_gate = (const float*)d_in[5];
    float* out = (float*)d_out;
    float* uc  = (float*)d_ws;  // 512 floats: u, c, W_llr, b_llr

    precompute_uc_kernel<<<1, 128, 0, stream>>>(W_llr, b_llr, W_gate, b_gate, uc);

    // 1875 compute blocks (5 tiles of 64 rows = 600000 rows exactly)
    // + 625 copy blocks, interleaved b&3==3. Total 2500.
    fused_residual_llr_kernel<<<2500, 256, 0, stream>>>(nf, llr, W_gate, uc, out);
}